// Round 18
// baseline (138.519 us; speedup 1.0000x reference)
//
#include <hip/hip_runtime.h>
#include <hip/hip_bf16.h>

// ---------------------------------------------------------------------------
// GCN layer: out = relu(segment_sum(adj_vals * (x@W)[cols], rows))
//   x: [50000,256] f32, W: [256,128] f32, edges: 800000
// 7-dispatch pipeline:
//  1. prep: zero deg[8][n] + split W into bf16 hi/lo transposed [col][k]
//  2. MFMA GEMM (split-bf16, 3 terms, bf16 out) — pure (R17 showed fused
//     hist tail serializes ~21us onto the dispatch; standalone is ~6us)
//  3. hist: partition-major slice counters deg[blockIdx&7][r], single-pass
//     grid-strided (XCD-local atomics, no 8x scanning)
//  4. scan1: per-block exclusive scan over (sum of 8 slices) + block sums
//  5. scan3: base = reduce(bsums[<b]) in-kernel + add
//  6. fill: destination-partitioned packed CSR (XCD-local atomics/stores)
//  7. gather: per-node unroll-8 accumulate + ReLU
// Fallback (ws too small / n_nodes too big): VALU GEMM + atomic scatter.
// ---------------------------------------------------------------------------

#define IN_F  256
#define OUT_F 128
#define NPART 8

#define BM 64        // rows per block (MFMA path)
#define BK 32        // fp32 K per step
#define KP 40        // padded K dim in LDS (bf16 elems)

typedef __attribute__((ext_vector_type(8))) short s16x8;
typedef __attribute__((ext_vector_type(4))) float f32x4;

static __device__ __forceinline__ unsigned short f2bf(float f) {
    union { float f; unsigned u; } v; v.f = f;
    unsigned r = v.u + 0x7FFFu + ((v.u >> 16) & 1u);   // RNE
    return (unsigned short)(r >> 16);
}
static __device__ __forceinline__ float bf2f(unsigned short b) {
    union { unsigned u; float f; } v; v.u = ((unsigned)b) << 16;
    return v.f;
}

// ---- Dispatch 1: prep = zero(deg[8][n]) + W split (hi/lo, transposed) -----
__global__ __launch_bounds__(256) void gcn_prep_kernel(
    const float* __restrict__ w, unsigned short* __restrict__ wh_T,
    unsigned short* __restrict__ wl_T, int* __restrict__ deg, int n_deg)
{
    int gid = blockIdx.x * 256 + threadIdx.x;

    // W split: cells (c, kq): 128 x 64 = 8192
    if (gid < OUT_F * IN_F / 4) {
        int c  = gid & (OUT_F - 1);
        int kq = gid >> 7;
        unsigned short h[4], l[4];
#pragma unroll
        for (int d = 0; d < 4; ++d) {
            float f = w[(size_t)(kq * 4 + d) * OUT_F + c];
            h[d] = f2bf(f);
            l[d] = f2bf(f - bf2f(h[d]));
        }
        *reinterpret_cast<ushort4*>(&wh_T[(size_t)c * IN_F + kq * 4]) =
            make_ushort4(h[0], h[1], h[2], h[3]);
        *reinterpret_cast<ushort4*>(&wl_T[(size_t)c * IN_F + kq * 4]) =
            make_ushort4(l[0], l[1], l[2], l[3]);
    }

    // zero deg (8 slices): one int4 per thread
    int base = gid * 4;
    if (base + 3 < n_deg) {
        *reinterpret_cast<int4*>(&deg[base]) = make_int4(0, 0, 0, 0);
    } else {
#pragma unroll
        for (int q = 0; q < 4; ++q)
            if (base + q < n_deg) deg[base + q] = 0;
    }
}

// ---------------- Dispatch 2: MFMA GEMM (split-bf16), bf16 out -------------
__global__ __launch_bounds__(256) void gcn_gemm_mfma_kernel(
    const float* __restrict__ x,
    const unsigned short* __restrict__ wh_T,
    const unsigned short* __restrict__ wl_T,
    unsigned short* __restrict__ support_bf, int n_nodes)
{
    __shared__ unsigned short xh_lds[BM][KP];
    __shared__ unsigned short xl_lds[BM][KP];
    __shared__ unsigned short wh_lds[OUT_F][KP];
    __shared__ unsigned short wl_lds[OUT_F][KP];

    const int tid  = threadIdx.x;
    const int lane = tid & 63;
    const int wid  = tid >> 6;
    const int wm   = (wid >> 1) * 32;
    const int wn   = (wid & 1) * 64;
    const int row0 = blockIdx.x * BM;

    const int lr = lane & 15;
    const int lg = lane >> 4;

    f32x4 acc[2][4];
#pragma unroll
    for (int st = 0; st < 2; ++st)
#pragma unroll
        for (int nt = 0; nt < 4; ++nt)
            acc[st][nt] = (f32x4){0.f, 0.f, 0.f, 0.f};

    for (int k0 = 0; k0 < IN_F; k0 += BK) {
        if (k0 > 0) __syncthreads();

#pragma unroll
        for (int i = 0; i < 2; ++i) {
            int cell = i * 256 + tid;
            int r    = cell >> 3;
            int kq   = cell & 7;
            int row  = row0 + r;
            float4 xv = make_float4(0.f, 0.f, 0.f, 0.f);
            if (row < n_nodes)
                xv = *reinterpret_cast<const float4*>(
                    &x[(size_t)row * IN_F + k0 + kq * 4]);
            unsigned short h0 = f2bf(xv.x), h1 = f2bf(xv.y),
                           h2 = f2bf(xv.z), h3 = f2bf(xv.w);
            *reinterpret_cast<ushort4*>(&xh_lds[r][kq * 4]) =
                make_ushort4(h0, h1, h2, h3);
            *reinterpret_cast<ushort4*>(&xl_lds[r][kq * 4]) =
                make_ushort4(f2bf(xv.x - bf2f(h0)), f2bf(xv.y - bf2f(h1)),
                             f2bf(xv.z - bf2f(h2)), f2bf(xv.w - bf2f(h3)));
        }
#pragma unroll
        for (int i = 0; i < 2; ++i) {
            int cell = i * 256 + tid;
            int c    = cell >> 2;
            int p    = cell & 3;
            s16x8 hv = *reinterpret_cast<const s16x8*>(
                &wh_T[(size_t)c * IN_F + k0 + p * 8]);
            s16x8 lv = *reinterpret_cast<const s16x8*>(
                &wl_T[(size_t)c * IN_F + k0 + p * 8]);
            *reinterpret_cast<s16x8*>(&wh_lds[c][p * 8]) = hv;
            *reinterpret_cast<s16x8*>(&wl_lds[c][p * 8]) = lv;
        }
        __syncthreads();

        s16x8 ah[2], al[2], bh[4], bl[4];
#pragma unroll
        for (int st = 0; st < 2; ++st) {
            int m = wm + st * 16 + lr;
            ah[st] = *reinterpret_cast<const s16x8*>(&xh_lds[m][lg * 8]);
            al[st] = *reinterpret_cast<const s16x8*>(&xl_lds[m][lg * 8]);
        }
#pragma unroll
        for (int nt = 0; nt < 4; ++nt) {
            int c = wn + nt * 16 + lr;
            bh[nt] = *reinterpret_cast<const s16x8*>(&wh_lds[c][lg * 8]);
            bl[nt] = *reinterpret_cast<const s16x8*>(&wl_lds[c][lg * 8]);
        }

#pragma unroll
        for (int st = 0; st < 2; ++st)
#pragma unroll
            for (int nt = 0; nt < 4; ++nt) {
                acc[st][nt] = __builtin_amdgcn_mfma_f32_16x16x32_bf16(
                    ah[st], bh[nt], acc[st][nt], 0, 0, 0);
                acc[st][nt] = __builtin_amdgcn_mfma_f32_16x16x32_bf16(
                    al[st], bh[nt], acc[st][nt], 0, 0, 0);
                acc[st][nt] = __builtin_amdgcn_mfma_f32_16x16x32_bf16(
                    ah[st], bl[nt], acc[st][nt], 0, 0, 0);
            }
    }

#pragma unroll
    for (int st = 0; st < 2; ++st) {
#pragma unroll
        for (int nt = 0; nt < 4; ++nt) {
#pragma unroll
            for (int r = 0; r < 4; ++r) {
                int m = row0 + wm + st * 16 + lg * 4 + r;
                int n = wn + nt * 16 + lr;
                if (m < n_nodes)
                    support_bf[(size_t)m * OUT_F + n] = f2bf(acc[st][nt][r]);
            }
        }
    }
}

// ------------------- Fallback Stage 1: VALU GEMM (proven R5) ---------------
#define VBK 32
#define XPAD 68
__global__ __launch_bounds__(256) void gcn_gemm_valu_kernel(
    const float* __restrict__ x, const float* __restrict__ w,
    float* __restrict__ support, int n_nodes)
{
    __shared__ float xs_t[VBK][XPAD];
    __shared__ float ws_[VBK][OUT_F];

    const int tid  = threadIdx.x;
    const int cg   = tid & 31;
    const int rg   = tid >> 5;
    const int row0 = blockIdx.x * BM;

    float acc[8][4];
#pragma unroll
    for (int i = 0; i < 8; ++i)
#pragma unroll
        for (int j = 0; j < 4; ++j) acc[i][j] = 0.f;

    for (int k0 = 0; k0 < IN_F; k0 += VBK) {
        if (k0 > 0) __syncthreads();
#pragma unroll
        for (int i = 0; i < 2; ++i) {
            int t   = tid + i * 256;
            int r   = t >> 3;
            int kk  = (t & 7) << 2;
            int row = row0 + r;
            float4 v = make_float4(0.f, 0.f, 0.f, 0.f);
            if (row < n_nodes)
                v = *reinterpret_cast<const float4*>(&x[(size_t)row * IN_F + k0 + kk]);
            xs_t[kk + 0][r] = v.x;
            xs_t[kk + 1][r] = v.y;
            xs_t[kk + 2][r] = v.z;
            xs_t[kk + 3][r] = v.w;
        }
#pragma unroll
        for (int i = 0; i < 4; ++i) {
            int fi = tid + i * 256;
            int kk = fi >> 5;
            int cc = (fi & 31) << 2;
            *reinterpret_cast<float4*>(&ws_[kk][cc]) =
                *reinterpret_cast<const float4*>(&w[(size_t)(k0 + kk) * OUT_F + cc]);
        }
        __syncthreads();
#pragma unroll
        for (int kk = 0; kk < VBK; ++kk) {
            float4 a0 = *reinterpret_cast<const float4*>(&xs_t[kk][rg * 4]);
            float4 a1 = *reinterpret_cast<const float4*>(&xs_t[kk][rg * 4 + 32]);
            float4 b  = *reinterpret_cast<const float4*>(&ws_[kk][cg * 4]);
            const float av[8] = {a0.x, a0.y, a0.z, a0.w, a1.x, a1.y, a1.z, a1.w};
            const float bv[4] = {b.x, b.y, b.z, b.w};
#pragma unroll
            for (int i = 0; i < 8; ++i)
#pragma unroll
                for (int j = 0; j < 4; ++j)
                    acc[i][j] += av[i] * bv[j];
        }
    }
#pragma unroll
    for (int i = 0; i < 8; ++i) {
        int row = row0 + rg * 4 + (i & 3) + (i >> 2) * 32;
        if (row < n_nodes) {
            float4 o = make_float4(acc[i][0], acc[i][1], acc[i][2], acc[i][3]);
            *reinterpret_cast<float4*>(&support[(size_t)row * OUT_F + cg * 4]) = o;
        }
    }
}

// ---- Dispatch 3: hist — partition-major slices, single pass ---------------
// Each edge visited exactly once across the grid; counts go into the slice
// matching this block's round-robin XCD (blockIdx&7). Any mapping is CORRECT
// (slices are summed in scan1); locality is perf-only.
__global__ __launch_bounds__(256) void gcn_hist_kernel(
    const int* __restrict__ rows, int* __restrict__ deg,
    int n_edges, int n_nodes)
{
    const size_t slice = (size_t)(blockIdx.x & 7) * n_nodes;
    const int stride   = gridDim.x * 256;
    for (int e = blockIdx.x * 256 + threadIdx.x; e < n_edges; e += stride)
        atomicAdd(&deg[slice + rows[e]], 1);
}

// ---- Dispatch 4: scan1 — exclusive scan of (sum of 8 deg slices) ----------
__global__ __launch_bounds__(256) void gcn_scan1_kernel(
    const int* __restrict__ deg, int* __restrict__ offsets,
    int* __restrict__ block_sums, int n)
{
    __shared__ int part[256];
    const int tid  = threadIdx.x;
    const int base = blockIdx.x * 2048 + tid * 8;

    int v[8];
#pragma unroll
    for (int q = 0; q < 8; ++q) v[q] = 0;
    if (base + 7 < n) {
#pragma unroll
        for (int p = 0; p < NPART; ++p) {
            const int* dp = deg + (size_t)p * n;
            int4 a = *reinterpret_cast<const int4*>(&dp[base]);
            int4 b = *reinterpret_cast<const int4*>(&dp[base + 4]);
            v[0] += a.x; v[1] += a.y; v[2] += a.z; v[3] += a.w;
            v[4] += b.x; v[5] += b.y; v[6] += b.z; v[7] += b.w;
        }
    } else {
#pragma unroll
        for (int q = 0; q < 8; ++q)
            if (base + q < n)
                for (int p = 0; p < NPART; ++p)
                    v[q] += deg[(size_t)p * n + base + q];
    }
    int s = 0;
#pragma unroll
    for (int q = 0; q < 8; ++q) s += v[q];
    part[tid] = s;
    __syncthreads();
    for (int d = 1; d < 256; d <<= 1) {
        int t = (tid >= d) ? part[tid - d] : 0;
        __syncthreads();
        part[tid] += t;
        __syncthreads();
    }
    int run = part[tid] - s;
    int o[8];
#pragma unroll
    for (int q = 0; q < 8; ++q) { o[q] = run; run += v[q]; }
    if (base + 7 < n) {
        *reinterpret_cast<int4*>(&offsets[base])     = make_int4(o[0], o[1], o[2], o[3]);
        *reinterpret_cast<int4*>(&offsets[base + 4]) = make_int4(o[4], o[5], o[6], o[7]);
    } else {
#pragma unroll
        for (int q = 0; q < 8; ++q)
            if (base + q < n) offsets[base + q] = o[q];
    }
    if (tid == 255) block_sums[blockIdx.x] = part[255];
}

// ---- Dispatch 5: scan3 — base = reduce(bsums[<b]) (scan2 merged) + add ----
__global__ __launch_bounds__(256) void gcn_scan3_kernel(
    int* __restrict__ offsets, const int* __restrict__ block_sums,
    int n, int nb)
{
    __shared__ int tmp[256];
    const int tid = threadIdx.x;
    int v = (tid < nb && tid < (int)blockIdx.x) ? block_sums[tid] : 0;
    tmp[tid] = v;
    __syncthreads();
#pragma unroll
    for (int d = 128; d > 0; d >>= 1) {
        if (tid < d) tmp[tid] += tmp[tid + d];
        __syncthreads();
    }
    const int add = tmp[0];

    const int base = blockIdx.x * 2048 + tid * 8;
    if (base + 7 < n) {
        int4 a = *reinterpret_cast<const int4*>(&offsets[base]);
        int4 b = *reinterpret_cast<const int4*>(&offsets[base + 4]);
        a.x += add; a.y += add; a.z += add; a.w += add;
        b.x += add; b.y += add; b.z += add; b.w += add;
        *reinterpret_cast<int4*>(&offsets[base])     = a;
        *reinterpret_cast<int4*>(&offsets[base + 4]) = b;
    } else {
#pragma unroll
        for (int q = 0; q < 8; ++q)
            if (base + q < n) offsets[base + q] += add;
    }
}

// ---- Dispatch 6: fill — destination-partitioned packed CSR ----------------
__global__ __launch_bounds__(256) void gcn_fill_kernel(
    const int* __restrict__ rows, const int* __restrict__ cols,
    const float* __restrict__ vals, int* __restrict__ offsets,
    unsigned int* __restrict__ csr_cv, int n_edges, int node_pp)
{
    int part = blockIdx.x & 7;
    int e = (blockIdx.x >> 3) * 256 + threadIdx.x;
    if (e >= n_edges) return;
    int r = rows[e];
    if (r / node_pp != part) return;
    int pos = atomicAdd(&offsets[r], 1);
    unsigned int cv = ((unsigned int)f2bf(vals[e]) << 16) | (unsigned int)cols[e];
    csr_cv[pos] = cv;
}

// ---- Dispatch 7: gather (unroll 8) + ReLU ---------------------------------
__global__ __launch_bounds__(256) void gcn_gather_kernel(
    const unsigned short* __restrict__ support_bf,
    const int* __restrict__ offsets,
    const unsigned int* __restrict__ csr_cv,
    float* __restrict__ out, int n_nodes)
{
    const int node = blockIdx.x * 4 + (threadIdx.x >> 6);
    const int lane = threadIdx.x & 63;
    if (node >= n_nodes) return;

    const int end   = offsets[node];
    const int start = (node == 0) ? 0 : offsets[node - 1];

    float2 acc = make_float2(0.f, 0.f);
    int j = start;
    for (; j + 7 < end; j += 8) {
        unsigned int cv[8];
        ushort2 s[8];
#pragma unroll
        for (int q = 0; q < 8; ++q) cv[q] = csr_cv[j + q];
#pragma unroll
        for (int q = 0; q < 8; ++q)
            s[q] = *reinterpret_cast<const ushort2*>(
                &support_bf[(size_t)(cv[q] & 0xFFFFu) * OUT_F + lane * 2]);
#pragma unroll
        for (int q = 0; q < 8; ++q) {
            float v = bf2f((unsigned short)(cv[q] >> 16));
            acc.x += v * bf2f(s[q].x);
            acc.y += v * bf2f(s[q].y);
        }
    }
    for (; j + 1 < end; j += 2) {
        unsigned int cv0 = csr_cv[j];
        unsigned int cv1 = csr_cv[j + 1];
        ushort2 s0 = *reinterpret_cast<const ushort2*>(
            &support_bf[(size_t)(cv0 & 0xFFFFu) * OUT_F + lane * 2]);
        ushort2 s1 = *reinterpret_cast<const ushort2*>(
            &support_bf[(size_t)(cv1 & 0xFFFFu) * OUT_F + lane * 2]);
        float v0 = bf2f((unsigned short)(cv0 >> 16));
        float v1 = bf2f((unsigned short)(cv1 >> 16));
        acc.x += v0 * bf2f(s0.x) + v1 * bf2f(s1.x);
        acc.y += v0 * bf2f(s0.y) + v1 * bf2f(s1.y);
    }
    if (j < end) {
        unsigned int cv0 = csr_cv[j];
        ushort2 s0 = *reinterpret_cast<const ushort2*>(
            &support_bf[(size_t)(cv0 & 0xFFFFu) * OUT_F + lane * 2]);
        float v0 = bf2f((unsigned short)(cv0 >> 16));
        acc.x += v0 * bf2f(s0.x);
        acc.y += v0 * bf2f(s0.y);
    }

    float2 o;
    o.x = fmaxf(acc.x, 0.f);
    o.y = fmaxf(acc.y, 0.f);
    *reinterpret_cast<float2*>(&out[(size_t)node * OUT_F + lane * 2]) = o;
}

// ------------------------- Fallback (atomic, f32 support) ------------------
__global__ __launch_bounds__(256) void gcn_scatter_kernel(
    const float* __restrict__ support, const float* __restrict__ vals,
    const int* __restrict__ rows, const int* __restrict__ cols,
    float* __restrict__ out, int n_edges)
{
    long long idx   = (long long)blockIdx.x * blockDim.x + threadIdx.x;
    long long total = (long long)n_edges * (OUT_F / 4);
    if (idx >= total) return;

    int e  = (int)(idx >> 5);
    int f4 = (int)(idx & 31);
    int r  = rows[e];
    int c  = cols[e];
    float v = vals[e];

    float4 s = *reinterpret_cast<const float4*>(&support[(size_t)c * OUT_F + f4 * 4]);
    float* o = &out[(size_t)r * OUT_F + f4 * 4];
    atomicAdd(o + 0, v * s.x);
    atomicAdd(o + 1, v * s.y);
    atomicAdd(o + 2, v * s.z);
    atomicAdd(o + 3, v * s.w);
}

__global__ __launch_bounds__(256) void gcn_relu_kernel(float* __restrict__ out, int n4)
{
    int idx = blockIdx.x * blockDim.x + threadIdx.x;
    if (idx >= n4) return;
    float4* p = reinterpret_cast<float4*>(out) + idx;
    float4 v = *p;
    v.x = fmaxf(v.x, 0.f);
    v.y = fmaxf(v.y, 0.f);
    v.z = fmaxf(v.z, 0.f);
    v.w = fmaxf(v.w, 0.f);
    *p = v;
}

// ---------------------------------------------------------------------------
static inline char* align16(char* p) {
    return (char*)(((uintptr_t)p + 15) & ~(uintptr_t)15);
}

extern "C" void kernel_launch(void* const* d_in, const int* in_sizes, int n_in,
                              void* d_out, int out_size, void* d_ws, size_t ws_size,
                              hipStream_t stream)
{
    const float* x    = (const float*)d_in[0];
    const float* w    = (const float*)d_in[1];
    const float* vals = (const float*)d_in[2];
    const int*   rows = (const int*)d_in[3];
    const int*   cols = (const int*)d_in[4];
    float* out = (float*)d_out;

    const int n_nodes = in_sizes[0] / IN_F;     // 50000
    const int n_edges = in_sizes[2];            // 800000

    const int scan_blocks = (n_nodes + 2047) / 2048;        // 25
    const int node_pp     = (n_nodes + NPART - 1) / NPART;  // 6250
    const int n_deg       = NPART * n_nodes;                // 400000

    // workspace layout (16B-aligned slots).
    char* p = (char*)d_ws;
    char*           supp_raw = p;                 p = align16(p + (size_t)n_nodes * OUT_F * sizeof(float));
    unsigned short* wh_T    = (unsigned short*)p; p = align16(p + (size_t)OUT_F * IN_F * sizeof(short));
    unsigned short* wl_T    = (unsigned short*)p; p = align16(p + (size_t)OUT_F * IN_F * sizeof(short));
    int*            offsets = (int*)p;            p = align16(p + (size_t)n_nodes * sizeof(int));
    int*            deg     = (int*)p;            p = align16(p + (size_t)n_deg * sizeof(int));
    int*            bsums   = (int*)p;            p = align16(p + (size_t)256 * sizeof(int));
    unsigned int*   csr_cv  = (unsigned int*)p;   p = align16(p + (size_t)n_edges * sizeof(unsigned int));
    size_t needed = (size_t)(p - (char*)d_ws);

    const int gemm_blocks = (n_nodes + BM - 1) / BM;
    const int eb = (n_edges + 255) / 256;

    if (ws_size >= needed && scan_blocks <= 256 && n_nodes <= 65536) {
        unsigned short* support_bf = (unsigned short*)supp_raw;

        // 1. prep: zero deg slices + W split
        int prep_blocks = max((OUT_F * IN_F / 4 + 255) / 256,
                              ((n_deg + 3) / 4 + 255) / 256);
        gcn_prep_kernel<<<prep_blocks, 256, 0, stream>>>(w, wh_T, wl_T, deg, n_deg);

        // 2. MFMA GEMM (pure)
        gcn_gemm_mfma_kernel<<<gemm_blocks, 256, 0, stream>>>(
            x, wh_T, wl_T, support_bf, n_nodes);

        // 3. hist (partition-major slices, single pass, XCD-local atomics)
        gcn_hist_kernel<<<2048, 256, 0, stream>>>(rows, deg, n_edges, n_nodes);

        // 4-5. scan (slice-summing scan1; scan2 merged into scan3)
        gcn_scan1_kernel<<<scan_blocks, 256, 0, stream>>>(deg, offsets, bsums, n_nodes);
        gcn_scan3_kernel<<<scan_blocks, 256, 0, stream>>>(offsets, bsums,
                                                          n_nodes, scan_blocks);

        // 6. fill (destination-partitioned)
        gcn_fill_kernel<<<eb * NPART, 256, 0, stream>>>(rows, cols, vals, offsets,
                                                        csr_cv, n_edges, node_pp);

        // 7. gather + fused ReLU
        int gb = (n_nodes + 3) / 4;
        gcn_gather_kernel<<<gb, 256, 0, stream>>>(support_bf, offsets,
                                                  csr_cv, out, n_nodes);
    } else {
        // fallback: VALU GEMM (f32 support) + atomic scatter
        float* support = (float*)supp_raw;
        gcn_gemm_valu_kernel<<<gemm_blocks, 256, 0, stream>>>(x, w, support, n_nodes);
        hipMemsetAsync(d_out, 0, (size_t)out_size * sizeof(float), stream);
        long long total = (long long)n_edges * (OUT_F / 4);
        int sc_blocks = (int)((total + 255) / 256);
        gcn_scatter_kernel<<<sc_blocks, 256, 0, stream>>>(support, vals, rows, cols,
                                                          out, n_edges);
        int n4 = out_size / 4;
        gcn_relu_kernel<<<(n4 + 255) / 256, 256, 0, stream>>>(out, n4);
    }
}

// Round 19
// 134.766 us; speedup vs baseline: 1.0279x; 1.0279x over previous
//
#include <hip/hip_runtime.h>
#include <hip/hip_bf16.h>

// ---------------------------------------------------------------------------
// GCN layer: out = relu(segment_sum(adj_vals * (x@W)[cols], rows))
//   x: [50000,256] f32, W: [256,128] f32, edges: 800000
// 6-dispatch pipeline (best measured: 135.7us, R17):
//  1. prep: zero deg[8][n] + split W into bf16 hi/lo transposed [col][k]
//  2. MFMA GEMM (split-bf16, 3 terms, bf16 out) + fused hist into
//     PARTITION-MAJOR counters deg[blockIdx&7][r] -> XCD-local atomics,
//     single pass over edges.
//  3. scan1: per-block exclusive scan over node degrees = sum of 8 slices
//  4. scan3: base = reduce(bsums[<b]) in-kernel + add
//  5. fill: destination-partitioned packed CSR (XCD-local atomics/stores)
//  6. gather: per-node unroll-8 accumulate + ReLU
// Fallback (ws too small / n_nodes too big): VALU GEMM + atomic scatter.
// ---------------------------------------------------------------------------

#define IN_F  256
#define OUT_F 128
#define NPART 8

#define BM 64        // rows per block (MFMA path)
#define BK 32        // fp32 K per step
#define KP 40        // padded K dim in LDS (bf16 elems)

typedef __attribute__((ext_vector_type(8))) short s16x8;
typedef __attribute__((ext_vector_type(4))) float f32x4;

static __device__ __forceinline__ unsigned short f2bf(float f) {
    union { float f; unsigned u; } v; v.f = f;
    unsigned r = v.u + 0x7FFFu + ((v.u >> 16) & 1u);   // RNE
    return (unsigned short)(r >> 16);
}
static __device__ __forceinline__ float bf2f(unsigned short b) {
    union { unsigned u; float f; } v; v.u = ((unsigned)b) << 16;
    return v.f;
}

// ---- Dispatch 1: prep = zero(deg[8][n]) + W split (hi/lo, transposed) -----
__global__ __launch_bounds__(256) void gcn_prep_kernel(
    const float* __restrict__ w, unsigned short* __restrict__ wh_T,
    unsigned short* __restrict__ wl_T, int* __restrict__ deg, int n_deg)
{
    int gid = blockIdx.x * 256 + threadIdx.x;

    // W split: cells (c, kq): 128 x 64 = 8192
    if (gid < OUT_F * IN_F / 4) {
        int c  = gid & (OUT_F - 1);
        int kq = gid >> 7;
        unsigned short h[4], l[4];
#pragma unroll
        for (int d = 0; d < 4; ++d) {
            float f = w[(size_t)(kq * 4 + d) * OUT_F + c];
            h[d] = f2bf(f);
            l[d] = f2bf(f - bf2f(h[d]));
        }
        *reinterpret_cast<ushort4*>(&wh_T[(size_t)c * IN_F + kq * 4]) =
            make_ushort4(h[0], h[1], h[2], h[3]);
        *reinterpret_cast<ushort4*>(&wl_T[(size_t)c * IN_F + kq * 4]) =
            make_ushort4(l[0], l[1], l[2], l[3]);
    }

    // zero deg (8 slices): one int4 per thread
    int base = gid * 4;
    if (base + 3 < n_deg) {
        *reinterpret_cast<int4*>(&deg[base]) = make_int4(0, 0, 0, 0);
    } else {
#pragma unroll
        for (int q = 0; q < 4; ++q)
            if (base + q < n_deg) deg[base + q] = 0;
    }
}

// -- Dispatch 2: MFMA GEMM (split-bf16) + fused hist into partition-major deg
__global__ __launch_bounds__(256) void gcn_gemm_mfma_kernel(
    const float* __restrict__ x,
    const unsigned short* __restrict__ wh_T,
    const unsigned short* __restrict__ wl_T,
    unsigned short* __restrict__ support_bf, int n_nodes,
    const int* __restrict__ rows, int* __restrict__ deg, int n_edges)
{
    __shared__ unsigned short xh_lds[BM][KP];
    __shared__ unsigned short xl_lds[BM][KP];
    __shared__ unsigned short wh_lds[OUT_F][KP];
    __shared__ unsigned short wl_lds[OUT_F][KP];

    const int tid  = threadIdx.x;
    const int lane = tid & 63;
    const int wid  = tid >> 6;
    const int wm   = (wid >> 1) * 32;
    const int wn   = (wid & 1) * 64;
    const int row0 = blockIdx.x * BM;

    const int lr = lane & 15;
    const int lg = lane >> 4;

    f32x4 acc[2][4];
#pragma unroll
    for (int st = 0; st < 2; ++st)
#pragma unroll
        for (int nt = 0; nt < 4; ++nt)
            acc[st][nt] = (f32x4){0.f, 0.f, 0.f, 0.f};

    for (int k0 = 0; k0 < IN_F; k0 += BK) {
        if (k0 > 0) __syncthreads();

#pragma unroll
        for (int i = 0; i < 2; ++i) {
            int cell = i * 256 + tid;
            int r    = cell >> 3;
            int kq   = cell & 7;
            int row  = row0 + r;
            float4 xv = make_float4(0.f, 0.f, 0.f, 0.f);
            if (row < n_nodes)
                xv = *reinterpret_cast<const float4*>(
                    &x[(size_t)row * IN_F + k0 + kq * 4]);
            unsigned short h0 = f2bf(xv.x), h1 = f2bf(xv.y),
                           h2 = f2bf(xv.z), h3 = f2bf(xv.w);
            *reinterpret_cast<ushort4*>(&xh_lds[r][kq * 4]) =
                make_ushort4(h0, h1, h2, h3);
            *reinterpret_cast<ushort4*>(&xl_lds[r][kq * 4]) =
                make_ushort4(f2bf(xv.x - bf2f(h0)), f2bf(xv.y - bf2f(h1)),
                             f2bf(xv.z - bf2f(h2)), f2bf(xv.w - bf2f(h3)));
        }
#pragma unroll
        for (int i = 0; i < 2; ++i) {
            int cell = i * 256 + tid;
            int c    = cell >> 2;
            int p    = cell & 3;
            s16x8 hv = *reinterpret_cast<const s16x8*>(
                &wh_T[(size_t)c * IN_F + k0 + p * 8]);
            s16x8 lv = *reinterpret_cast<const s16x8*>(
                &wl_T[(size_t)c * IN_F + k0 + p * 8]);
            *reinterpret_cast<s16x8*>(&wh_lds[c][p * 8]) = hv;
            *reinterpret_cast<s16x8*>(&wl_lds[c][p * 8]) = lv;
        }
        __syncthreads();

        s16x8 ah[2], al[2], bh[4], bl[4];
#pragma unroll
        for (int st = 0; st < 2; ++st) {
            int m = wm + st * 16 + lr;
            ah[st] = *reinterpret_cast<const s16x8*>(&xh_lds[m][lg * 8]);
            al[st] = *reinterpret_cast<const s16x8*>(&xl_lds[m][lg * 8]);
        }
#pragma unroll
        for (int nt = 0; nt < 4; ++nt) {
            int c = wn + nt * 16 + lr;
            bh[nt] = *reinterpret_cast<const s16x8*>(&wh_lds[c][lg * 8]);
            bl[nt] = *reinterpret_cast<const s16x8*>(&wl_lds[c][lg * 8]);
        }

#pragma unroll
        for (int st = 0; st < 2; ++st)
#pragma unroll
            for (int nt = 0; nt < 4; ++nt) {
                acc[st][nt] = __builtin_amdgcn_mfma_f32_16x16x32_bf16(
                    ah[st], bh[nt], acc[st][nt], 0, 0, 0);
                acc[st][nt] = __builtin_amdgcn_mfma_f32_16x16x32_bf16(
                    al[st], bh[nt], acc[st][nt], 0, 0, 0);
                acc[st][nt] = __builtin_amdgcn_mfma_f32_16x16x32_bf16(
                    ah[st], bl[nt], acc[st][nt], 0, 0, 0);
            }
    }

#pragma unroll
    for (int st = 0; st < 2; ++st) {
#pragma unroll
        for (int nt = 0; nt < 4; ++nt) {
#pragma unroll
            for (int r = 0; r < 4; ++r) {
                int m = row0 + wm + st * 16 + lg * 4 + r;
                int n = wn + nt * 16 + lr;
                if (m < n_nodes)
                    support_bf[(size_t)m * OUT_F + n] = f2bf(acc[st][nt][r]);
            }
        }
    }

    // --- fused histogram: single pass over this block's edge chunks (every
    // edge visited exactly once across the grid), counting into the slice
    // owned by this block's XCD (blockIdx&7, round-robin heuristic). Any
    // mapping is CORRECT (slices are summed in scan1); locality is perf-only.
    const size_t slice = (size_t)(blockIdx.x & 7) * n_nodes;
    const int estride  = gridDim.x * 256;
    for (int e = blockIdx.x * 256 + tid; e < n_edges; e += estride)
        atomicAdd(&deg[slice + rows[e]], 1);
}

// ------------------- Fallback Stage 1: VALU GEMM (proven R5) ---------------
#define VBK 32
#define XPAD 68
__global__ __launch_bounds__(256) void gcn_gemm_valu_kernel(
    const float* __restrict__ x, const float* __restrict__ w,
    float* __restrict__ support, int n_nodes)
{
    __shared__ float xs_t[VBK][XPAD];
    __shared__ float ws_[VBK][OUT_F];

    const int tid  = threadIdx.x;
    const int cg   = tid & 31;
    const int rg   = tid >> 5;
    const int row0 = blockIdx.x * BM;

    float acc[8][4];
#pragma unroll
    for (int i = 0; i < 8; ++i)
#pragma unroll
        for (int j = 0; j < 4; ++j) acc[i][j] = 0.f;

    for (int k0 = 0; k0 < IN_F; k0 += VBK) {
        if (k0 > 0) __syncthreads();
#pragma unroll
        for (int i = 0; i < 2; ++i) {
            int t   = tid + i * 256;
            int r   = t >> 3;
            int kk  = (t & 7) << 2;
            int row = row0 + r;
            float4 v = make_float4(0.f, 0.f, 0.f, 0.f);
            if (row < n_nodes)
                v = *reinterpret_cast<const float4*>(&x[(size_t)row * IN_F + k0 + kk]);
            xs_t[kk + 0][r] = v.x;
            xs_t[kk + 1][r] = v.y;
            xs_t[kk + 2][r] = v.z;
            xs_t[kk + 3][r] = v.w;
        }
#pragma unroll
        for (int i = 0; i < 4; ++i) {
            int fi = tid + i * 256;
            int kk = fi >> 5;
            int cc = (fi & 31) << 2;
            *reinterpret_cast<float4*>(&ws_[kk][cc]) =
                *reinterpret_cast<const float4*>(&w[(size_t)(k0 + kk) * OUT_F + cc]);
        }
        __syncthreads();
#pragma unroll
        for (int kk = 0; kk < VBK; ++kk) {
            float4 a0 = *reinterpret_cast<const float4*>(&xs_t[kk][rg * 4]);
            float4 a1 = *reinterpret_cast<const float4*>(&xs_t[kk][rg * 4 + 32]);
            float4 b  = *reinterpret_cast<const float4*>(&ws_[kk][cg * 4]);
            const float av[8] = {a0.x, a0.y, a0.z, a0.w, a1.x, a1.y, a1.z, a1.w};
            const float bv[4] = {b.x, b.y, b.z, b.w};
#pragma unroll
            for (int i = 0; i < 8; ++i)
#pragma unroll
                for (int j = 0; j < 4; ++j)
                    acc[i][j] += av[i] * bv[j];
        }
    }
#pragma unroll
    for (int i = 0; i < 8; ++i) {
        int row = row0 + rg * 4 + (i & 3) + (i >> 2) * 32;
        if (row < n_nodes) {
            float4 o = make_float4(acc[i][0], acc[i][1], acc[i][2], acc[i][3]);
            *reinterpret_cast<float4*>(&support[(size_t)row * OUT_F + cg * 4]) = o;
        }
    }
}

// ---- Dispatch 3: scan1 — exclusive scan of (sum of 8 deg slices) ----------
__global__ __launch_bounds__(256) void gcn_scan1_kernel(
    const int* __restrict__ deg, int* __restrict__ offsets,
    int* __restrict__ block_sums, int n)
{
    __shared__ int part[256];
    const int tid  = threadIdx.x;
    const int base = blockIdx.x * 2048 + tid * 8;

    int v[8];
#pragma unroll
    for (int q = 0; q < 8; ++q) v[q] = 0;
    if (base + 7 < n) {
#pragma unroll
        for (int p = 0; p < NPART; ++p) {
            const int* dp = deg + (size_t)p * n;
            int4 a = *reinterpret_cast<const int4*>(&dp[base]);
            int4 b = *reinterpret_cast<const int4*>(&dp[base + 4]);
            v[0] += a.x; v[1] += a.y; v[2] += a.z; v[3] += a.w;
            v[4] += b.x; v[5] += b.y; v[6] += b.z; v[7] += b.w;
        }
    } else {
#pragma unroll
        for (int q = 0; q < 8; ++q)
            if (base + q < n)
                for (int p = 0; p < NPART; ++p)
                    v[q] += deg[(size_t)p * n + base + q];
    }
    int s = 0;
#pragma unroll
    for (int q = 0; q < 8; ++q) s += v[q];
    part[tid] = s;
    __syncthreads();
    for (int d = 1; d < 256; d <<= 1) {
        int t = (tid >= d) ? part[tid - d] : 0;
        __syncthreads();
        part[tid] += t;
        __syncthreads();
    }
    int run = part[tid] - s;
    int o[8];
#pragma unroll
    for (int q = 0; q < 8; ++q) { o[q] = run; run += v[q]; }
    if (base + 7 < n) {
        *reinterpret_cast<int4*>(&offsets[base])     = make_int4(o[0], o[1], o[2], o[3]);
        *reinterpret_cast<int4*>(&offsets[base + 4]) = make_int4(o[4], o[5], o[6], o[7]);
    } else {
#pragma unroll
        for (int q = 0; q < 8; ++q)
            if (base + q < n) offsets[base + q] = o[q];
    }
    if (tid == 255) block_sums[blockIdx.x] = part[255];
}

// ---- Dispatch 4: scan3 — base = reduce(bsums[<b]) (scan2 merged) + add ----
__global__ __launch_bounds__(256) void gcn_scan3_kernel(
    int* __restrict__ offsets, const int* __restrict__ block_sums,
    int n, int nb)
{
    __shared__ int tmp[256];
    const int tid = threadIdx.x;
    int v = (tid < nb && tid < (int)blockIdx.x) ? block_sums[tid] : 0;
    tmp[tid] = v;
    __syncthreads();
#pragma unroll
    for (int d = 128; d > 0; d >>= 1) {
        if (tid < d) tmp[tid] += tmp[tid + d];
        __syncthreads();
    }
    const int add = tmp[0];

    const int base = blockIdx.x * 2048 + tid * 8;
    if (base + 7 < n) {
        int4 a = *reinterpret_cast<const int4*>(&offsets[base]);
        int4 b = *reinterpret_cast<const int4*>(&offsets[base + 4]);
        a.x += add; a.y += add; a.z += add; a.w += add;
        b.x += add; b.y += add; b.z += add; b.w += add;
        *reinterpret_cast<int4*>(&offsets[base])     = a;
        *reinterpret_cast<int4*>(&offsets[base + 4]) = b;
    } else {
#pragma unroll
        for (int q = 0; q < 8; ++q)
            if (base + q < n) offsets[base + q] += add;
    }
}

// ---- Dispatch 5: fill — destination-partitioned packed CSR ----------------
__global__ __launch_bounds__(256) void gcn_fill_kernel(
    const int* __restrict__ rows, const int* __restrict__ cols,
    const float* __restrict__ vals, int* __restrict__ offsets,
    unsigned int* __restrict__ csr_cv, int n_edges, int node_pp)
{
    int part = blockIdx.x & 7;
    int e = (blockIdx.x >> 3) * 256 + threadIdx.x;
    if (e >= n_edges) return;
    int r = rows[e];
    if (r / node_pp != part) return;
    int pos = atomicAdd(&offsets[r], 1);
    unsigned int cv = ((unsigned int)f2bf(vals[e]) << 16) | (unsigned int)cols[e];
    csr_cv[pos] = cv;
}

// ---- Dispatch 6: gather (unroll 8) + ReLU ---------------------------------
__global__ __launch_bounds__(256) void gcn_gather_kernel(
    const unsigned short* __restrict__ support_bf,
    const int* __restrict__ offsets,
    const unsigned int* __restrict__ csr_cv,
    float* __restrict__ out, int n_nodes)
{
    const int node = blockIdx.x * 4 + (threadIdx.x >> 6);
    const int lane = threadIdx.x & 63;
    if (node >= n_nodes) return;

    const int end   = offsets[node];
    const int start = (node == 0) ? 0 : offsets[node - 1];

    float2 acc = make_float2(0.f, 0.f);
    int j = start;
    for (; j + 7 < end; j += 8) {
        unsigned int cv[8];
        ushort2 s[8];
#pragma unroll
        for (int q = 0; q < 8; ++q) cv[q] = csr_cv[j + q];
#pragma unroll
        for (int q = 0; q < 8; ++q)
            s[q] = *reinterpret_cast<const ushort2*>(
                &support_bf[(size_t)(cv[q] & 0xFFFFu) * OUT_F + lane * 2]);
#pragma unroll
        for (int q = 0; q < 8; ++q) {
            float v = bf2f((unsigned short)(cv[q] >> 16));
            acc.x += v * bf2f(s[q].x);
            acc.y += v * bf2f(s[q].y);
        }
    }
    for (; j + 1 < end; j += 2) {
        unsigned int cv0 = csr_cv[j];
        unsigned int cv1 = csr_cv[j + 1];
        ushort2 s0 = *reinterpret_cast<const ushort2*>(
            &support_bf[(size_t)(cv0 & 0xFFFFu) * OUT_F + lane * 2]);
        ushort2 s1 = *reinterpret_cast<const ushort2*>(
            &support_bf[(size_t)(cv1 & 0xFFFFu) * OUT_F + lane * 2]);
        float v0 = bf2f((unsigned short)(cv0 >> 16));
        float v1 = bf2f((unsigned short)(cv1 >> 16));
        acc.x += v0 * bf2f(s0.x) + v1 * bf2f(s1.x);
        acc.y += v0 * bf2f(s0.y) + v1 * bf2f(s1.y);
    }
    if (j < end) {
        unsigned int cv0 = csr_cv[j];
        ushort2 s0 = *reinterpret_cast<const ushort2*>(
            &support_bf[(size_t)(cv0 & 0xFFFFu) * OUT_F + lane * 2]);
        float v0 = bf2f((unsigned short)(cv0 >> 16));
        acc.x += v0 * bf2f(s0.x);
        acc.y += v0 * bf2f(s0.y);
    }

    float2 o;
    o.x = fmaxf(acc.x, 0.f);
    o.y = fmaxf(acc.y, 0.f);
    *reinterpret_cast<float2*>(&out[(size_t)node * OUT_F + lane * 2]) = o;
}

// ------------------------- Fallback (atomic, f32 support) ------------------
__global__ __launch_bounds__(256) void gcn_scatter_kernel(
    const float* __restrict__ support, const float* __restrict__ vals,
    const int* __restrict__ rows, const int* __restrict__ cols,
    float* __restrict__ out, int n_edges)
{
    long long idx   = (long long)blockIdx.x * blockDim.x + threadIdx.x;
    long long total = (long long)n_edges * (OUT_F / 4);
    if (idx >= total) return;

    int e  = (int)(idx >> 5);
    int f4 = (int)(idx & 31);
    int r  = rows[e];
    int c  = cols[e];
    float v = vals[e];

    float4 s = *reinterpret_cast<const float4*>(&support[(size_t)c * OUT_F + f4 * 4]);
    float* o = &out[(size_t)r * OUT_F + f4 * 4];
    atomicAdd(o + 0, v * s.x);
    atomicAdd(o + 1, v * s.y);
    atomicAdd(o + 2, v * s.z);
    atomicAdd(o + 3, v * s.w);
}

__global__ __launch_bounds__(256) void gcn_relu_kernel(float* __restrict__ out, int n4)
{
    int idx = blockIdx.x * blockDim.x + threadIdx.x;
    if (idx >= n4) return;
    float4* p = reinterpret_cast<float4*>(out) + idx;
    float4 v = *p;
    v.x = fmaxf(v.x, 0.f);
    v.y = fmaxf(v.y, 0.f);
    v.z = fmaxf(v.z, 0.f);
    v.w = fmaxf(v.w, 0.f);
    *p = v;
}

// ---------------------------------------------------------------------------
static inline char* align16(char* p) {
    return (char*)(((uintptr_t)p + 15) & ~(uintptr_t)15);
}

extern "C" void kernel_launch(void* const* d_in, const int* in_sizes, int n_in,
                              void* d_out, int out_size, void* d_ws, size_t ws_size,
                              hipStream_t stream)
{
    const float* x    = (const float*)d_in[0];
    const float* w    = (const float*)d_in[1];
    const float* vals = (const float*)d_in[2];
    const int*   rows = (const int*)d_in[3];
    const int*   cols = (const int*)d_in[4];
    float* out = (float*)d_out;

    const int n_nodes = in_sizes[0] / IN_F;     // 50000
    const int n_edges = in_sizes[2];            // 800000

    const int scan_blocks = (n_nodes + 2047) / 2048;        // 25
    const int node_pp     = (n_nodes + NPART - 1) / NPART;  // 6250
    const int n_deg       = NPART * n_nodes;                // 400000

    // workspace layout (16B-aligned slots).
    char* p = (char*)d_ws;
    char*           supp_raw = p;                 p = align16(p + (size_t)n_nodes * OUT_F * sizeof(float));
    unsigned short* wh_T    = (unsigned short*)p; p = align16(p + (size_t)OUT_F * IN_F * sizeof(short));
    unsigned short* wl_T    = (unsigned short*)p; p = align16(p + (size_t)OUT_F * IN_F * sizeof(short));
    int*            offsets = (int*)p;            p = align16(p + (size_t)n_nodes * sizeof(int));
    int*            deg     = (int*)p;            p = align16(p + (size_t)n_deg * sizeof(int));
    int*            bsums   = (int*)p;            p = align16(p + (size_t)256 * sizeof(int));
    unsigned int*   csr_cv  = (unsigned int*)p;   p = align16(p + (size_t)n_edges * sizeof(unsigned int));
    size_t needed = (size_t)(p - (char*)d_ws);

    const int gemm_blocks = (n_nodes + BM - 1) / BM;
    const int eb = (n_edges + 255) / 256;

    if (ws_size >= needed && scan_blocks <= 256 && n_nodes <= 65536) {
        unsigned short* support_bf = (unsigned short*)supp_raw;

        // 1. prep: zero deg slices + W split
        int prep_blocks = max((OUT_F * IN_F / 4 + 255) / 256,
                              ((n_deg + 3) / 4 + 255) / 256);
        gcn_prep_kernel<<<prep_blocks, 256, 0, stream>>>(w, wh_T, wl_T, deg, n_deg);

        // 2. MFMA GEMM + fused partition-major histogram
        gcn_gemm_mfma_kernel<<<gemm_blocks, 256, 0, stream>>>(
            x, wh_T, wl_T, support_bf, n_nodes, rows, deg, n_edges);

        // 3-4. scan (slice-summing scan1; scan2 merged into scan3)
        gcn_scan1_kernel<<<scan_blocks, 256, 0, stream>>>(deg, offsets, bsums, n_nodes);
        gcn_scan3_kernel<<<scan_blocks, 256, 0, stream>>>(offsets, bsums,
                                                          n_nodes, scan_blocks);

        // 5. fill (destination-partitioned)
        gcn_fill_kernel<<<eb * NPART, 256, 0, stream>>>(rows, cols, vals, offsets,
                                                        csr_cv, n_edges, node_pp);

        // 6. gather + fused ReLU
        int gb = (n_nodes + 3) / 4;
        gcn_gather_kernel<<<gb, 256, 0, stream>>>(support_bf, offsets,
                                                  csr_cv, out, n_nodes);
    } else {
        // fallback: VALU GEMM (f32 support) + atomic scatter
        float* support = (float*)supp_raw;
        gcn_gemm_valu_kernel<<<gemm_blocks, 256, 0, stream>>>(x, w, support, n_nodes);
        hipMemsetAsync(d_out, 0, (size_t)out_size * sizeof(float), stream);
        long long total = (long long)n_edges * (OUT_F / 4);
        int sc_blocks = (int)((total + 255) / 256);
        gcn_scatter_kernel<<<sc_blocks, 256, 0, stream>>>(support, vals, rows, cols,
                                                          out, n_edges);
        int n4 = out_size / 4;
        gcn_relu_kernel<<<(n4 + 255) / 256, 256, 0, stream>>>(out, n4);
    }
}